// Round 8
// baseline (234.169 us; speedup 1.0000x reference)
//
#include <hip/hip_runtime.h>

// SVD_Solver: weighted Kabsch per (batch, joint).  B=4096, M=64, J=24.
// Round 11: isolate TLP. R10b (joint-pair float2) REGRESSED 44->52us ->
// VMEM-instruction count is not the bottleneck; reverted. All structures show
// mem 14-18%, VALU 20-41%, Occ ~30% -> latency/occupancy-bound. R9b (best,
// 44us) had only 16 waves/CU. This round: R9b's exact per-lane pattern, but
// each batch split across TWO waves (m-halves) -> 8192 waves; VGPR capped 64
// via __launch_bounds__(256,8) -> 32 waves/CU, whole grid co-resident
// (grid 2048 = 8 blocks/CU, 7.4KB LDS). Per-wave loads halve (112), wave
// count doubles. Cross-wave combine in LDS; 2 barriers; 48 solves on wave 0.

constexpr int M = 64;
constexpr int J = 24;
constexpr int NACC = 22;          // W, Wo[3], Wp[3], To[3], Tp[3], Sraw[9]
constexpr int NWS  = 15;          // S[9], Pbar[3], Qbar[3]
constexpr int BPB  = 2;           // batches per block (4 waves, 2 per batch)

// ---- fast Jacobi rotation: single-instruction rcp/rsq/sqrt ----
template<int P, int Q>
__device__ __forceinline__ void jrot(float A[4][4], float V[4][4]) {
    float apq = A[P][Q];
    float theta = (A[Q][Q] - A[P][P]) * __builtin_amdgcn_rcpf(2.0f * apq);
    float t = __builtin_amdgcn_rcpf(fabsf(theta) + __builtin_amdgcn_sqrtf(fmaf(theta, theta, 1.0f)));
    t = (theta < 0.0f) ? -t : t;
    t = (apq == 0.0f) ? 0.0f : t;            // kills inf/NaN from rcp(0)
    float c = __builtin_amdgcn_rsqf(fmaf(t, t, 1.0f));
    float s = t * c;
#pragma unroll
    for (int k = 0; k < 4; ++k) {
        float akp = A[k][P], akq = A[k][Q];
        A[k][P] = c * akp - s * akq;
        A[k][Q] = s * akp + c * akq;
    }
#pragma unroll
    for (int k = 0; k < 4; ++k) {
        float apk = A[P][k], aqk = A[Q][k];
        A[P][k] = c * apk - s * aqk;
        A[Q][k] = s * apk + c * aqk;
        float vkp = V[k][P], vkq = V[k][Q];
        V[k][P] = c * vkp - s * vkq;
        V[k][Q] = s * vkp + c * vkq;
    }
}

__device__ __forceinline__ void horn_solve(
    float S00, float S01, float S02, float S10, float S11, float S12,
    float S20, float S21, float S22,
    float cP0, float cP1, float cP2, float cQ0, float cQ1, float cQ2,
    float* __restrict__ Rout, float* __restrict__ tout)
{
    float A[4][4], V[4][4];
    A[0][0] = S00 + S11 + S22;
    A[0][1] = A[1][0] = S12 - S21;
    A[0][2] = A[2][0] = S20 - S02;
    A[0][3] = A[3][0] = S01 - S10;
    A[1][1] = S00 - S11 - S22;
    A[1][2] = A[2][1] = S01 + S10;
    A[1][3] = A[3][1] = S02 + S20;
    A[2][2] = -S00 + S11 - S22;
    A[2][3] = A[3][2] = S12 + S21;
    A[3][3] = -S00 - S11 + S22;
#pragma unroll
    for (int r = 0; r < 4; ++r)
#pragma unroll
        for (int c = 0; c < 4; ++c)
            V[r][c] = (r == c) ? 1.0f : 0.0f;

#pragma unroll 1
    for (int sweep = 0; sweep < 6; ++sweep) {
        jrot<0, 1>(A, V); jrot<0, 2>(A, V); jrot<0, 3>(A, V);
        jrot<1, 2>(A, V); jrot<1, 3>(A, V); jrot<2, 3>(A, V);
    }

    float best = A[0][0];
    float qw = V[0][0], qx = V[1][0], qy = V[2][0], qz = V[3][0];
#pragma unroll
    for (int i = 1; i < 4; ++i) {
        bool better = A[i][i] > best;
        best = better ? A[i][i] : best;
        qw = better ? V[0][i] : qw;
        qx = better ? V[1][i] : qx;
        qy = better ? V[2][i] : qy;
        qz = better ? V[3][i] : qz;
    }
    float nrm = __builtin_amdgcn_rsqf(qw * qw + qx * qx + qy * qy + qz * qz);
    qw *= nrm; qx *= nrm; qy *= nrm; qz *= nrm;

    float R00 = 1.f - 2.f * (qy * qy + qz * qz);
    float R01 = 2.f * (qx * qy - qw * qz);
    float R02 = 2.f * (qx * qz + qw * qy);
    float R10 = 2.f * (qx * qy + qw * qz);
    float R11 = 1.f - 2.f * (qx * qx + qz * qz);
    float R12 = 2.f * (qy * qz - qw * qx);
    float R20 = 2.f * (qx * qz - qw * qy);
    float R21 = 2.f * (qy * qz + qw * qx);
    float R22 = 1.f - 2.f * (qx * qx + qy * qy);

    Rout[0] = R00; Rout[1] = R01; Rout[2] = R02;
    Rout[3] = R10; Rout[4] = R11; Rout[5] = R12;
    Rout[6] = R20; Rout[7] = R21; Rout[8] = R22;
    tout[0] = cQ0 - (R00 * cP0 + R01 * cP1 + R02 * cP2);
    tout[1] = cQ1 - (R10 * cP0 + R11 * cP1 + R12 * cP2);
    tout[2] = cQ2 - (R20 * cP0 + R21 * cP1 + R22 * cP2);
}

// ---- half-batch-per-wave fused: grid = ceil(B/BPB) x 256 threads ----
__global__ __launch_bounds__(256, 8) void kabsch_fused(
    const float* __restrict__ points,   // (B, 64, 3)
    const float* __restrict__ weight,   // (B, 64, 24)
    const float* __restrict__ offset,   // (B, 64, 24, 3)
    float* __restrict__ out,            // R (bj,9) then t (bj,3)
    int B, int bj_total)
{
    const int t    = threadIdx.x;
    const int wv   = t >> 6;             // wave 0..3
    const int g    = wv >> 1;            // batch slot in block (0,1)
    const int h    = wv & 1;             // m-half: m in [h*32, h*32+32)
    const int lane = t & 63;
    const int jj   = lane >> 1;          // joint 0..31 (24..31 masked)
    const int kk   = lane & 1;           // m-parity within half

    int bw = blockIdx.x * BPB + g;
    bw = bw < B ? bw : B - 1;            // clamp keeps wave alive for barriers

    __shared__ float part[BPB][NACC][J + 1];   // h==1 partials, 4.4 KB
    __shared__ float sv_s[BPB][NWS][J + 1];    // Sv handoff, 3.0 KB

    float acc[NACC];
#pragma unroll
    for (int n = 0; n < NACC; ++n) acc[n] = 0.0f;

    if (jj < J) {
        // m = h*32 + i*2 + kk, i = 0..15  (identical per-lane pattern to R9b,
        // just half the m-range per wave)
        const int m0 = h * 32 + kk;
        const float* wq = weight + (size_t)bw * (M * J)     + (size_t)m0 * J + jj;
        const float* oq = offset + (size_t)bw * (M * J * 3) + (size_t)m0 * (J * 3) + jj * 3;
        const float* pq = points + (size_t)bw * (M * 3)     + (size_t)m0 * 3;

#pragma unroll
        for (int i = 0; i < 16; ++i) {
            float w  = wq[i * 48];          // stride 2 m's = 48 floats
            float o0 = oq[i * 144 + 0];
            float o1 = oq[i * 144 + 1];
            float o2 = oq[i * 144 + 2];
            float p0 = pq[i * 6 + 0];
            float p1 = pq[i * 6 + 1];
            float p2 = pq[i * 6 + 2];
            acc[0] += w;
            acc[1] = fmaf(w, o0, acc[1]);  acc[2] = fmaf(w, o1, acc[2]);  acc[3] = fmaf(w, o2, acc[3]);
            acc[4] = fmaf(w, p0, acc[4]);  acc[5] = fmaf(w, p1, acc[5]);  acc[6] = fmaf(w, p2, acc[6]);
            acc[7] += o0; acc[8] += o1; acc[9] += o2;
            acc[10] += p0; acc[11] += p1; acc[12] += p2;
            acc[13] = fmaf(o0, p0, acc[13]); acc[14] = fmaf(o0, p1, acc[14]); acc[15] = fmaf(o0, p2, acc[15]);
            acc[16] = fmaf(o1, p0, acc[16]); acc[17] = fmaf(o1, p1, acc[17]); acc[18] = fmaf(o1, p2, acc[18]);
            acc[19] = fmaf(o2, p0, acc[19]); acc[20] = fmaf(o2, p1, acc[20]); acc[21] = fmaf(o2, p2, acc[21]);
        }

        // reduce over kk (lane^1)
#pragma unroll
        for (int n = 0; n < NACC; ++n) acc[n] += __shfl_xor(acc[n], 1);

        // m-half h==1 publishes partials
        if (h == 1 && kk == 0) {
#pragma unroll
            for (int n = 0; n < NACC; ++n) part[g][n][jj] = acc[n];
        }
    }

    __syncthreads();

    if (jj < J && h == 0 && kk == 0) {
#pragma unroll
        for (int n = 0; n < NACC; ++n) acc[n] += part[g][n][jj];

        const float inv = __builtin_amdgcn_rcpf(acc[0]);
        const float cP0 = acc[1] * inv, cP1 = acc[2] * inv, cP2 = acc[3] * inv;
        const float cQ0 = acc[4] * inv, cQ1 = acc[5] * inv, cQ2 = acc[6] * inv;
        const float To0 = acc[7], To1 = acc[8], To2 = acc[9];
        const float Tp0 = acc[10], Tp1 = acc[11], Tp2 = acc[12];
        const float fM = (float)M;
        sv_s[g][0][jj]  = acc[13] - cP0 * Tp0 - cQ0 * To0 + fM * cP0 * cQ0;
        sv_s[g][1][jj]  = acc[14] - cP0 * Tp1 - cQ1 * To0 + fM * cP0 * cQ1;
        sv_s[g][2][jj]  = acc[15] - cP0 * Tp2 - cQ2 * To0 + fM * cP0 * cQ2;
        sv_s[g][3][jj]  = acc[16] - cP1 * Tp0 - cQ0 * To1 + fM * cP1 * cQ0;
        sv_s[g][4][jj]  = acc[17] - cP1 * Tp1 - cQ1 * To1 + fM * cP1 * cQ1;
        sv_s[g][5][jj]  = acc[18] - cP1 * Tp2 - cQ2 * To1 + fM * cP1 * cQ2;
        sv_s[g][6][jj]  = acc[19] - cP2 * Tp0 - cQ0 * To2 + fM * cP2 * cQ0;
        sv_s[g][7][jj]  = acc[20] - cP2 * Tp1 - cQ1 * To2 + fM * cP2 * cQ1;
        sv_s[g][8][jj]  = acc[21] - cP2 * Tp2 - cQ2 * To2 + fM * cP2 * cQ2;
        sv_s[g][9][jj]  = cP0; sv_s[g][10][jj] = cP1; sv_s[g][11][jj] = cP2;
        sv_s[g][12][jj] = cQ0; sv_s[g][13][jj] = cQ1; sv_s[g][14][jj] = cQ2;
    }

    __syncthreads();

    // solve phase: threads 0..47 (wave 0), one Horn solve each
    if (t < BPB * J) {
        const int gs = t / J;
        const int j  = t - gs * J;
        int bb = blockIdx.x * BPB + gs;
        if (bb < B) {
            float v[NWS];
#pragma unroll
            for (int n = 0; n < NWS; ++n) v[n] = sv_s[gs][n][j];
            float Rr[9], tr[3];
            horn_solve(v[0], v[1], v[2], v[3], v[4], v[5], v[6], v[7], v[8],
                       v[9], v[10], v[11], v[12], v[13], v[14], Rr, tr);
            const int bj = bb * J + j;
            float* Rout = out + (size_t)bj * 9;
#pragma unroll
            for (int n = 0; n < 9; ++n) Rout[n] = Rr[n];
            float* tout = out + (size_t)bj_total * 9 + (size_t)bj * 3;
            tout[0] = tr[0]; tout[1] = tr[1]; tout[2] = tr[2];
        }
    }
}

extern "C" void kernel_launch(void* const* d_in, const int* in_sizes, int n_in,
                              void* d_out, int out_size, void* d_ws, size_t ws_size,
                              hipStream_t stream) {
    const float* points = (const float*)d_in[0];
    const float* weight = (const float*)d_in[1];
    const float* offset = (const float*)d_in[2];
    float* out = (float*)d_out;

    int B = in_sizes[0] / (M * 3);
    int bj_total = B * J;
    int grid = (B + BPB - 1) / BPB;

    kabsch_fused<<<grid, 256, 0, stream>>>(points, weight, offset, out, B, bj_total);
}

// Round 9
// 154.382 us; speedup vs baseline: 1.5168x; 1.5168x over previous
//
#include <hip/hip_runtime.h>

// SVD_Solver: weighted Kabsch per (batch, joint).  B=4096, M=64, J=24.
// Round 12: R11 retry WITHOUT the spill. R11's __launch_bounds__(256,8)
// forced VGPR=32 -> 22 accumulators spilled to scratch (WRITE_SIZE 4.6->143MB,
// kernel 44->140us, scratch-BW-bound). The TLP hypothesis was never tested.
// This round: identical 2-waves-per-batch structure, __launch_bounds__(256,4)
// (128-VGPR budget, no spill; R9b's identical body compiled to 64 VGPR).
// If compiler lands <=64 VGPR -> HW can run 8 waves/SIMD and the 8192 waves
// give a true 32 waves/CU: the clean TLP experiment.
// Structure: block = 256 thr = 4 waves = 2 batches x 2 m-halves. Per wave:
// R9b's exact per-lane scalar-load pattern over 16 m's, shfl pair-reduce,
// h==1 publishes partials to LDS, h==0 combines + writes Sv, 48 solves on
// wave 0. 2 barriers, 7.4 KB LDS.

constexpr int M = 64;
constexpr int J = 24;
constexpr int NACC = 22;          // W, Wo[3], Wp[3], To[3], Tp[3], Sraw[9]
constexpr int NWS  = 15;          // S[9], Pbar[3], Qbar[3]
constexpr int BPB  = 2;           // batches per block (4 waves, 2 per batch)

// ---- fast Jacobi rotation: single-instruction rcp/rsq/sqrt ----
template<int P, int Q>
__device__ __forceinline__ void jrot(float A[4][4], float V[4][4]) {
    float apq = A[P][Q];
    float theta = (A[Q][Q] - A[P][P]) * __builtin_amdgcn_rcpf(2.0f * apq);
    float t = __builtin_amdgcn_rcpf(fabsf(theta) + __builtin_amdgcn_sqrtf(fmaf(theta, theta, 1.0f)));
    t = (theta < 0.0f) ? -t : t;
    t = (apq == 0.0f) ? 0.0f : t;            // kills inf/NaN from rcp(0)
    float c = __builtin_amdgcn_rsqf(fmaf(t, t, 1.0f));
    float s = t * c;
#pragma unroll
    for (int k = 0; k < 4; ++k) {
        float akp = A[k][P], akq = A[k][Q];
        A[k][P] = c * akp - s * akq;
        A[k][Q] = s * akp + c * akq;
    }
#pragma unroll
    for (int k = 0; k < 4; ++k) {
        float apk = A[P][k], aqk = A[Q][k];
        A[P][k] = c * apk - s * aqk;
        A[Q][k] = s * apk + c * aqk;
        float vkp = V[k][P], vkq = V[k][Q];
        V[k][P] = c * vkp - s * vkq;
        V[k][Q] = s * vkp + c * vkq;
    }
}

__device__ __forceinline__ void horn_solve(
    float S00, float S01, float S02, float S10, float S11, float S12,
    float S20, float S21, float S22,
    float cP0, float cP1, float cP2, float cQ0, float cQ1, float cQ2,
    float* __restrict__ Rout, float* __restrict__ tout)
{
    float A[4][4], V[4][4];
    A[0][0] = S00 + S11 + S22;
    A[0][1] = A[1][0] = S12 - S21;
    A[0][2] = A[2][0] = S20 - S02;
    A[0][3] = A[3][0] = S01 - S10;
    A[1][1] = S00 - S11 - S22;
    A[1][2] = A[2][1] = S01 + S10;
    A[1][3] = A[3][1] = S02 + S20;
    A[2][2] = -S00 + S11 - S22;
    A[2][3] = A[3][2] = S12 + S21;
    A[3][3] = -S00 - S11 + S22;
#pragma unroll
    for (int r = 0; r < 4; ++r)
#pragma unroll
        for (int c = 0; c < 4; ++c)
            V[r][c] = (r == c) ? 1.0f : 0.0f;

#pragma unroll 1
    for (int sweep = 0; sweep < 6; ++sweep) {
        jrot<0, 1>(A, V); jrot<0, 2>(A, V); jrot<0, 3>(A, V);
        jrot<1, 2>(A, V); jrot<1, 3>(A, V); jrot<2, 3>(A, V);
    }

    float best = A[0][0];
    float qw = V[0][0], qx = V[1][0], qy = V[2][0], qz = V[3][0];
#pragma unroll
    for (int i = 1; i < 4; ++i) {
        bool better = A[i][i] > best;
        best = better ? A[i][i] : best;
        qw = better ? V[0][i] : qw;
        qx = better ? V[1][i] : qx;
        qy = better ? V[2][i] : qy;
        qz = better ? V[3][i] : qz;
    }
    float nrm = __builtin_amdgcn_rsqf(qw * qw + qx * qx + qy * qy + qz * qz);
    qw *= nrm; qx *= nrm; qy *= nrm; qz *= nrm;

    float R00 = 1.f - 2.f * (qy * qy + qz * qz);
    float R01 = 2.f * (qx * qy - qw * qz);
    float R02 = 2.f * (qx * qz + qw * qy);
    float R10 = 2.f * (qx * qy + qw * qz);
    float R11 = 1.f - 2.f * (qx * qx + qz * qz);
    float R12 = 2.f * (qy * qz - qw * qx);
    float R20 = 2.f * (qx * qz - qw * qy);
    float R21 = 2.f * (qy * qz + qw * qx);
    float R22 = 1.f - 2.f * (qx * qx + qy * qy);

    Rout[0] = R00; Rout[1] = R01; Rout[2] = R02;
    Rout[3] = R10; Rout[4] = R11; Rout[5] = R12;
    Rout[6] = R20; Rout[7] = R21; Rout[8] = R22;
    tout[0] = cQ0 - (R00 * cP0 + R01 * cP1 + R02 * cP2);
    tout[1] = cQ1 - (R10 * cP0 + R11 * cP1 + R12 * cP2);
    tout[2] = cQ2 - (R20 * cP0 + R21 * cP1 + R22 * cP2);
}

// ---- half-batch-per-wave fused: grid = ceil(B/BPB) x 256 threads ----
__global__ __launch_bounds__(256, 4) void kabsch_fused(
    const float* __restrict__ points,   // (B, 64, 3)
    const float* __restrict__ weight,   // (B, 64, 24)
    const float* __restrict__ offset,   // (B, 64, 24, 3)
    float* __restrict__ out,            // R (bj,9) then t (bj,3)
    int B, int bj_total)
{
    const int t    = threadIdx.x;
    const int wv   = t >> 6;             // wave 0..3
    const int g    = wv >> 1;            // batch slot in block (0,1)
    const int h    = wv & 1;             // m-half: m in [h*32, h*32+32)
    const int lane = t & 63;
    const int jj   = lane >> 1;          // joint 0..31 (24..31 masked)
    const int kk   = lane & 1;           // m-parity within half

    int bw = blockIdx.x * BPB + g;
    bw = bw < B ? bw : B - 1;            // clamp keeps wave alive for barriers

    __shared__ float part[BPB][NACC][J + 1];   // h==1 partials, 4.4 KB
    __shared__ float sv_s[BPB][NWS][J + 1];    // Sv handoff, 3.0 KB

    float acc[NACC];
#pragma unroll
    for (int n = 0; n < NACC; ++n) acc[n] = 0.0f;

    if (jj < J) {
        // m = h*32 + kk + i*2, i = 0..15  (R9b's per-lane pattern, half range)
        const int m0 = h * 32 + kk;
        const float* wq = weight + (size_t)bw * (M * J)     + (size_t)m0 * J + jj;
        const float* oq = offset + (size_t)bw * (M * J * 3) + (size_t)m0 * (J * 3) + jj * 3;
        const float* pq = points + (size_t)bw * (M * 3)     + (size_t)m0 * 3;

#pragma unroll
        for (int i = 0; i < 16; ++i) {
            float w  = wq[i * 48];          // stride 2 m's = 48 floats
            float o0 = oq[i * 144 + 0];
            float o1 = oq[i * 144 + 1];
            float o2 = oq[i * 144 + 2];
            float p0 = pq[i * 6 + 0];
            float p1 = pq[i * 6 + 1];
            float p2 = pq[i * 6 + 2];
            acc[0] += w;
            acc[1] = fmaf(w, o0, acc[1]);  acc[2] = fmaf(w, o1, acc[2]);  acc[3] = fmaf(w, o2, acc[3]);
            acc[4] = fmaf(w, p0, acc[4]);  acc[5] = fmaf(w, p1, acc[5]);  acc[6] = fmaf(w, p2, acc[6]);
            acc[7] += o0; acc[8] += o1; acc[9] += o2;
            acc[10] += p0; acc[11] += p1; acc[12] += p2;
            acc[13] = fmaf(o0, p0, acc[13]); acc[14] = fmaf(o0, p1, acc[14]); acc[15] = fmaf(o0, p2, acc[15]);
            acc[16] = fmaf(o1, p0, acc[16]); acc[17] = fmaf(o1, p1, acc[17]); acc[18] = fmaf(o1, p2, acc[18]);
            acc[19] = fmaf(o2, p0, acc[19]); acc[20] = fmaf(o2, p1, acc[20]); acc[21] = fmaf(o2, p2, acc[21]);
        }

        // reduce over kk (lane^1)
#pragma unroll
        for (int n = 0; n < NACC; ++n) acc[n] += __shfl_xor(acc[n], 1);

        // m-half h==1 publishes partials
        if (h == 1 && kk == 0) {
#pragma unroll
            for (int n = 0; n < NACC; ++n) part[g][n][jj] = acc[n];
        }
    }

    __syncthreads();

    if (jj < J && h == 0 && kk == 0) {
#pragma unroll
        for (int n = 0; n < NACC; ++n) acc[n] += part[g][n][jj];

        const float inv = __builtin_amdgcn_rcpf(acc[0]);
        const float cP0 = acc[1] * inv, cP1 = acc[2] * inv, cP2 = acc[3] * inv;
        const float cQ0 = acc[4] * inv, cQ1 = acc[5] * inv, cQ2 = acc[6] * inv;
        const float To0 = acc[7], To1 = acc[8], To2 = acc[9];
        const float Tp0 = acc[10], Tp1 = acc[11], Tp2 = acc[12];
        const float fM = (float)M;
        sv_s[g][0][jj]  = acc[13] - cP0 * Tp0 - cQ0 * To0 + fM * cP0 * cQ0;
        sv_s[g][1][jj]  = acc[14] - cP0 * Tp1 - cQ1 * To0 + fM * cP0 * cQ1;
        sv_s[g][2][jj]  = acc[15] - cP0 * Tp2 - cQ2 * To0 + fM * cP0 * cQ2;
        sv_s[g][3][jj]  = acc[16] - cP1 * Tp0 - cQ0 * To1 + fM * cP1 * cQ0;
        sv_s[g][4][jj]  = acc[17] - cP1 * Tp1 - cQ1 * To1 + fM * cP1 * cQ1;
        sv_s[g][5][jj]  = acc[18] - cP1 * Tp2 - cQ2 * To1 + fM * cP1 * cQ2;
        sv_s[g][6][jj]  = acc[19] - cP2 * Tp0 - cQ0 * To2 + fM * cP2 * cQ0;
        sv_s[g][7][jj]  = acc[20] - cP2 * Tp1 - cQ1 * To2 + fM * cP2 * cQ1;
        sv_s[g][8][jj]  = acc[21] - cP2 * Tp2 - cQ2 * To2 + fM * cP2 * cQ2;
        sv_s[g][9][jj]  = cP0; sv_s[g][10][jj] = cP1; sv_s[g][11][jj] = cP2;
        sv_s[g][12][jj] = cQ0; sv_s[g][13][jj] = cQ1; sv_s[g][14][jj] = cQ2;
    }

    __syncthreads();

    // solve phase: threads 0..47 (wave 0), one Horn solve each
    if (t < BPB * J) {
        const int gs = t / J;
        const int j  = t - gs * J;
        int bb = blockIdx.x * BPB + gs;
        if (bb < B) {
            float v[NWS];
#pragma unroll
            for (int n = 0; n < NWS; ++n) v[n] = sv_s[gs][n][j];
            float Rr[9], tr[3];
            horn_solve(v[0], v[1], v[2], v[3], v[4], v[5], v[6], v[7], v[8],
                       v[9], v[10], v[11], v[12], v[13], v[14], Rr, tr);
            const int bj = bb * J + j;
            float* Rout = out + (size_t)bj * 9;
#pragma unroll
            for (int n = 0; n < 9; ++n) Rout[n] = Rr[n];
            float* tout = out + (size_t)bj_total * 9 + (size_t)bj * 3;
            tout[0] = tr[0]; tout[1] = tr[1]; tout[2] = tr[2];
        }
    }
}

extern "C" void kernel_launch(void* const* d_in, const int* in_sizes, int n_in,
                              void* d_out, int out_size, void* d_ws, size_t ws_size,
                              hipStream_t stream) {
    const float* points = (const float*)d_in[0];
    const float* weight = (const float*)d_in[1];
    const float* offset = (const float*)d_in[2];
    float* out = (float*)d_out;

    int B = in_sizes[0] / (M * 3);
    int bj_total = B * J;
    int grid = (B + BPB - 1) / BPB;

    kabsch_fused<<<grid, 256, 0, stream>>>(points, weight, offset, out, B, bj_total);
}

// Round 10
// 140.060 us; speedup vs baseline: 1.6719x; 1.1023x over previous
//
#include <hip/hip_runtime.h>

// SVD_Solver: weighted Kabsch per (batch, joint).  B=4096, M=64, J=24.
// FINAL (revert to R9b, the empirical best: dur_us 140.2, kernel ~44us).
// Optimization ledger (9 measured rounds):
//   - BW:        warm(4.7MB)==cold(50MB) duration -> not BW-bound      (R2)
//   - dispatch:  4096->1024 blocks: -6%                                 (R3)
//   - barriers:  8 -> 1 per block: -10%                                 (R9b)
//   - VMEM width: scalar->float2 (halved instr count): +20% WORSE       (R10b)
//   - TLP:       16 -> 32 waves/CU (no spill, VGPR=64): +25% WORSE      (R12)
//   - VGPR cap:  forced 32 VGPR -> 143MB scratch spill (control)        (R11)
// Conclusion: remaining ~44us vs ~17us BW floor is a latency/clock-ramp
// floor for this tiny burst kernel; timed window additionally carries
// ~90-100us of harness poison fills. No structural lever remains.
// Structure: each 64-lane wave owns ONE batch. lane=(jj,kk): jj=joint(0..23),
// kk=m-half. Direct scalar global loads (proven fastest), 32-iter unrolled
// accum, ONE shfl_xor pair-reduce, Sv -> 1.5KB LDS, ONE barrier, 48 Horn
// solves on wave 0. 128-thread blocks, grid B/2.

constexpr int M = 64;
constexpr int J = 24;
constexpr int NACC = 22;          // W, Wo[3], Wp[3], To[3], Tp[3], Sraw[9]
constexpr int NWS  = 15;          // S[9], Pbar[3], Qbar[3]
constexpr int WPB  = 2;           // waves (=batches) per block

// ---- fast Jacobi rotation: single-instruction rcp/rsq/sqrt ----
template<int P, int Q>
__device__ __forceinline__ void jrot(float A[4][4], float V[4][4]) {
    float apq = A[P][Q];
    float theta = (A[Q][Q] - A[P][P]) * __builtin_amdgcn_rcpf(2.0f * apq);
    float t = __builtin_amdgcn_rcpf(fabsf(theta) + __builtin_amdgcn_sqrtf(fmaf(theta, theta, 1.0f)));
    t = (theta < 0.0f) ? -t : t;
    t = (apq == 0.0f) ? 0.0f : t;            // kills inf/NaN from rcp(0)
    float c = __builtin_amdgcn_rsqf(fmaf(t, t, 1.0f));
    float s = t * c;
#pragma unroll
    for (int k = 0; k < 4; ++k) {
        float akp = A[k][P], akq = A[k][Q];
        A[k][P] = c * akp - s * akq;
        A[k][Q] = s * akp + c * akq;
    }
#pragma unroll
    for (int k = 0; k < 4; ++k) {
        float apk = A[P][k], aqk = A[Q][k];
        A[P][k] = c * apk - s * aqk;
        A[Q][k] = s * apk + c * aqk;
        float vkp = V[k][P], vkq = V[k][Q];
        V[k][P] = c * vkp - s * vkq;
        V[k][Q] = s * vkp + c * vkq;
    }
}

__device__ __forceinline__ void horn_solve(
    float S00, float S01, float S02, float S10, float S11, float S12,
    float S20, float S21, float S22,
    float cP0, float cP1, float cP2, float cQ0, float cQ1, float cQ2,
    float* __restrict__ Rout, float* __restrict__ tout)
{
    float A[4][4], V[4][4];
    A[0][0] = S00 + S11 + S22;
    A[0][1] = A[1][0] = S12 - S21;
    A[0][2] = A[2][0] = S20 - S02;
    A[0][3] = A[3][0] = S01 - S10;
    A[1][1] = S00 - S11 - S22;
    A[1][2] = A[2][1] = S01 + S10;
    A[1][3] = A[3][1] = S02 + S20;
    A[2][2] = -S00 + S11 - S22;
    A[2][3] = A[3][2] = S12 + S21;
    A[3][3] = -S00 - S11 + S22;
#pragma unroll
    for (int r = 0; r < 4; ++r)
#pragma unroll
        for (int c = 0; c < 4; ++c)
            V[r][c] = (r == c) ? 1.0f : 0.0f;

#pragma unroll 1
    for (int sweep = 0; sweep < 6; ++sweep) {
        jrot<0, 1>(A, V); jrot<0, 2>(A, V); jrot<0, 3>(A, V);
        jrot<1, 2>(A, V); jrot<1, 3>(A, V); jrot<2, 3>(A, V);
    }

    float best = A[0][0];
    float qw = V[0][0], qx = V[1][0], qy = V[2][0], qz = V[3][0];
#pragma unroll
    for (int i = 1; i < 4; ++i) {
        bool better = A[i][i] > best;
        best = better ? A[i][i] : best;
        qw = better ? V[0][i] : qw;
        qx = better ? V[1][i] : qx;
        qy = better ? V[2][i] : qy;
        qz = better ? V[3][i] : qz;
    }
    float nrm = __builtin_amdgcn_rsqf(qw * qw + qx * qx + qy * qy + qz * qz);
    qw *= nrm; qx *= nrm; qy *= nrm; qz *= nrm;

    float R00 = 1.f - 2.f * (qy * qy + qz * qz);
    float R01 = 2.f * (qx * qy - qw * qz);
    float R02 = 2.f * (qx * qz + qw * qy);
    float R10 = 2.f * (qx * qy + qw * qz);
    float R11 = 1.f - 2.f * (qx * qx + qz * qz);
    float R12 = 2.f * (qy * qz - qw * qx);
    float R20 = 2.f * (qx * qz - qw * qy);
    float R21 = 2.f * (qy * qz + qw * qx);
    float R22 = 1.f - 2.f * (qx * qx + qy * qy);

    Rout[0] = R00; Rout[1] = R01; Rout[2] = R02;
    Rout[3] = R10; Rout[4] = R11; Rout[5] = R12;
    Rout[6] = R20; Rout[7] = R21; Rout[8] = R22;
    tout[0] = cQ0 - (R00 * cP0 + R01 * cP1 + R02 * cP2);
    tout[1] = cQ1 - (R10 * cP0 + R11 * cP1 + R12 * cP2);
    tout[2] = cQ2 - (R20 * cP0 + R21 * cP1 + R22 * cP2);
}

// ---- wave-per-batch fused: grid = ceil(B/WPB) x 128 threads ----
__global__ __launch_bounds__(128, 4) void kabsch_fused(
    const float* __restrict__ points,   // (B, 64, 3)
    const float* __restrict__ weight,   // (B, 64, 24)
    const float* __restrict__ offset,   // (B, 64, 24, 3)
    float* __restrict__ out,            // R (bj,9) then t (bj,3)
    int B, int bj_total)
{
    const int t    = threadIdx.x;
    const int wv   = t >> 6;             // wave in block = batch slot
    const int lane = t & 63;
    const int jj   = lane >> 1;          // joint 0..31 (24..31 masked)
    const int kk   = lane & 1;           // m-half: m in [kk*32, kk*32+32)

    int bw = blockIdx.x * WPB + wv;
    bw = bw < B ? bw : B - 1;            // clamp keeps wave alive for barrier

    __shared__ float sv_s[WPB][NWS][J + 1];   // 1.5 KB prepadded handoff

    if (jj < J) {
        const float* wq = weight + (size_t)bw * (M * J) + (size_t)(kk * 32) * J + jj;
        const float* oq = offset + (size_t)bw * (M * J * 3) + (size_t)(kk * 32) * (J * 3) + jj * 3;
        const float* pq = points + (size_t)bw * (M * 3) + (size_t)(kk * 32) * 3;

        float acc[NACC];
#pragma unroll
        for (int n = 0; n < NACC; ++n) acc[n] = 0.0f;

        // 32 fully-independent iterations: loads pipeline across the unroll,
        // no barriers, no LDS in the accum path.
#pragma unroll
        for (int i = 0; i < M / 2; ++i) {
            float w  = wq[i * J];
            float o0 = oq[i * 72 + 0];
            float o1 = oq[i * 72 + 1];
            float o2 = oq[i * 72 + 2];
            float p0 = pq[i * 3 + 0];
            float p1 = pq[i * 3 + 1];
            float p2 = pq[i * 3 + 2];
            acc[0] += w;
            acc[1] = fmaf(w, o0, acc[1]);  acc[2] = fmaf(w, o1, acc[2]);  acc[3] = fmaf(w, o2, acc[3]);
            acc[4] = fmaf(w, p0, acc[4]);  acc[5] = fmaf(w, p1, acc[5]);  acc[6] = fmaf(w, p2, acc[6]);
            acc[7] += o0; acc[8] += o1; acc[9] += o2;
            acc[10] += p0; acc[11] += p1; acc[12] += p2;
            acc[13] = fmaf(o0, p0, acc[13]); acc[14] = fmaf(o0, p1, acc[14]); acc[15] = fmaf(o0, p2, acc[15]);
            acc[16] = fmaf(o1, p0, acc[16]); acc[17] = fmaf(o1, p1, acc[17]); acc[18] = fmaf(o1, p2, acc[18]);
            acc[19] = fmaf(o2, p0, acc[19]); acc[20] = fmaf(o2, p1, acc[20]); acc[21] = fmaf(o2, p2, acc[21]);
        }

        // pair-reduce over kk (lane^1): 22 cross-lane ops total
#pragma unroll
        for (int n = 0; n < NACC; ++n) acc[n] += __shfl_xor(acc[n], 1);

        if (kk == 0) {
            const float inv = __builtin_amdgcn_rcpf(acc[0]);
            const float cP0 = acc[1] * inv, cP1 = acc[2] * inv, cP2 = acc[3] * inv;
            const float cQ0 = acc[4] * inv, cQ1 = acc[5] * inv, cQ2 = acc[6] * inv;
            const float To0 = acc[7], To1 = acc[8], To2 = acc[9];
            const float Tp0 = acc[10], Tp1 = acc[11], Tp2 = acc[12];
            const float fM = (float)M;
            sv_s[wv][0][jj]  = acc[13] - cP0 * Tp0 - cQ0 * To0 + fM * cP0 * cQ0;
            sv_s[wv][1][jj]  = acc[14] - cP0 * Tp1 - cQ1 * To0 + fM * cP0 * cQ1;
            sv_s[wv][2][jj]  = acc[15] - cP0 * Tp2 - cQ2 * To0 + fM * cP0 * cQ2;
            sv_s[wv][3][jj]  = acc[16] - cP1 * Tp0 - cQ0 * To1 + fM * cP1 * cQ0;
            sv_s[wv][4][jj]  = acc[17] - cP1 * Tp1 - cQ1 * To1 + fM * cP1 * cQ1;
            sv_s[wv][5][jj]  = acc[18] - cP1 * Tp2 - cQ2 * To1 + fM * cP1 * cQ2;
            sv_s[wv][6][jj]  = acc[19] - cP2 * Tp0 - cQ0 * To2 + fM * cP2 * cQ0;
            sv_s[wv][7][jj]  = acc[20] - cP2 * Tp1 - cQ1 * To2 + fM * cP2 * cQ1;
            sv_s[wv][8][jj]  = acc[21] - cP2 * Tp2 - cQ2 * To2 + fM * cP2 * cQ2;
            sv_s[wv][9][jj]  = cP0; sv_s[wv][10][jj] = cP1; sv_s[wv][11][jj] = cP2;
            sv_s[wv][12][jj] = cQ0; sv_s[wv][13][jj] = cQ1; sv_s[wv][14][jj] = cQ2;
        }
    }

    __syncthreads();   // the ONLY barrier

    // solve phase: threads 0..47 (wave 0), one Horn solve each; wave 1 retires
    if (t < WPB * J) {
        const int g  = t / J;
        const int j  = t - g * J;
        int bb = blockIdx.x * WPB + g;
        if (bb < B) {
            float v[NWS];
#pragma unroll
            for (int n = 0; n < NWS; ++n) v[n] = sv_s[g][n][j];
            float Rr[9], tr[3];
            horn_solve(v[0], v[1], v[2], v[3], v[4], v[5], v[6], v[7], v[8],
                       v[9], v[10], v[11], v[12], v[13], v[14], Rr, tr);
            const int bj = bb * J + j;
            float* Rout = out + (size_t)bj * 9;
#pragma unroll
            for (int n = 0; n < 9; ++n) Rout[n] = Rr[n];
            float* tout = out + (size_t)bj_total * 9 + (size_t)bj * 3;
            tout[0] = tr[0]; tout[1] = tr[1]; tout[2] = tr[2];
        }
    }
}

extern "C" void kernel_launch(void* const* d_in, const int* in_sizes, int n_in,
                              void* d_out, int out_size, void* d_ws, size_t ws_size,
                              hipStream_t stream) {
    const float* points = (const float*)d_in[0];
    const float* weight = (const float*)d_in[1];
    const float* offset = (const float*)d_in[2];
    float* out = (float*)d_out;

    int B = in_sizes[0] / (M * 3);
    int bj_total = B * J;
    int grid = (B + WPB - 1) / WPB;

    kabsch_fused<<<grid, 128, 0, stream>>>(points, weight, offset, out, B, bj_total);
}